// Round 1
// baseline (88.120 us; speedup 1.0000x reference)
//
#include <hip/hip_runtime.h>
#include <math.h>

#define DIMK 1024
#define BATCH 32
#define YLD 1025       // y / out leading dim (dim+1)
#define DT_C 0.01f

// ---------------- Kernel 1: prep ----------------
// One block per batch b. Computes sin/cos of phases into ws in [j][b] layout
// (so kernel 2 can stage contiguous chunks), and f1[b] = sum_j cforce[b,j]^2.
__global__ __launch_bounds__(256) void kura_prep(
    const float* __restrict__ t,
    const float* __restrict__ y,
    const float* __restrict__ u,
    float* __restrict__ out,
    float* __restrict__ ws_sin,
    float* __restrict__ ws_cos) {
    const int b = blockIdx.x;
    const int tid = threadIdx.x;
    const int idx = (int)floorf(t[0] / DT_C);

    const float* yb = y + (size_t)b * YLD;
    const float* ub = u + (size_t)idx * BATCH * DIMK + (size_t)b * DIMK;

    float acc = 0.f;
    #pragma unroll
    for (int q = 0; q < DIMK / 256; q++) {
        int j = tid + q * 256;
        float p = yb[j];
        float s = sinf(p);
        float c = cosf(p);
        ws_sin[j * BATCH + b] = s;
        ws_cos[j * BATCH + b] = c;
        float f = ub[j];
        acc = fmaf(f, f, acc);
    }
    // block reduce (4 waves of 64)
    __shared__ float red[4];
    for (int off = 32; off > 0; off >>= 1)
        acc += __shfl_down(acc, off, 64);
    if ((tid & 63) == 0) red[tid >> 6] = acc;
    __syncthreads();
    if (tid == 0)
        out[(size_t)b * YLD + DIMK] = red[0] + red[1] + red[2] + red[3];
}

// ---------------- Kernel 2: main ----------------
// coupling[b,i] = cos(pi)*dot(A[i,:],sinP[b,:]) - sin(pi)*dot(A[i,:],cosP[b,:])
// Block: 4 rows x 32 batches, K split across two thread-halves.
#define RPB 4
#define JC 128

__global__ __launch_bounds__(256) void kura_main(
    const float* __restrict__ t,
    const float* __restrict__ u,
    const float* __restrict__ A,
    const float* __restrict__ freqs,
    const float* __restrict__ ws_sin,
    const float* __restrict__ ws_cos,
    float* __restrict__ out) {
    __shared__ float A_lds[RPB][JC];
    __shared__ float S_lds[JC][BATCH];
    __shared__ float C_lds[JC][BATCH];
    __shared__ float red_s[128], red_c[128];

    const int tid = threadIdx.x;
    const int b  = tid & 31;
    const int r  = (tid >> 5) & 3;
    const int kh = tid >> 7;                 // 0 or 1: K-half
    const int row0 = blockIdx.x * RPB;

    const int idx = (int)floorf(t[0] / DT_C);

    float acc_s = 0.f, acc_c = 0.f;

    for (int j0 = 0; j0 < DIMK; j0 += JC) {
        // A tile: RPB*JC = 512 floats -> 256 threads x float2 (coalesced rows)
        {
            int lin = tid * 2;
            int rr = lin >> 7;               // / JC
            int jj = lin & (JC - 1);
            float2 a2 = *(const float2*)(A + (size_t)(row0 + rr) * DIMK + j0 + jj);
            *(float2*)&A_lds[rr][jj] = a2;
        }
        // S/C tiles: JC*32 = 4096 floats each, contiguous in ws ([j][b] layout)
        {
            const float4* src_s = (const float4*)(ws_sin + (size_t)j0 * BATCH);
            const float4* src_c = (const float4*)(ws_cos + (size_t)j0 * BATCH);
            float4* dst_s = (float4*)&S_lds[0][0];
            float4* dst_c = (float4*)&C_lds[0][0];
            #pragma unroll
            for (int q = 0; q < 4; q++) {
                dst_s[tid + q * 256] = src_s[tid + q * 256];
                dst_c[tid + q * 256] = src_c[tid + q * 256];
            }
        }
        __syncthreads();
        const int jbase = kh * (JC / 2);
        #pragma unroll 16
        for (int jj = 0; jj < JC / 2; jj++) {
            float a = A_lds[r][jbase + jj];
            float s = S_lds[jbase + jj][b];
            float c = C_lds[jbase + jj][b];
            acc_s = fmaf(a, s, acc_s);
            acc_c = fmaf(a, c, acc_c);
        }
        __syncthreads();
    }

    // combine the two K-halves
    if (kh == 1) { red_s[tid - 128] = acc_s; red_c[tid - 128] = acc_c; }
    __syncthreads();
    if (kh == 0) {
        acc_s += red_s[tid];
        acc_c += red_c[tid];
        const int i = row0 + r;
        float sin_pi = ws_sin[i * BATCH + b];
        float cos_pi = ws_cos[i * BATCH + b];
        float coupling = cos_pi * acc_s - sin_pi * acc_c;
        float cf = u[(size_t)idx * BATCH * DIMK + (size_t)b * DIMK + i];
        out[(size_t)b * YLD + i] = fmaf(cf * coupling, 1.0f / DIMK, freqs[i]);
    }
}

extern "C" void kernel_launch(void* const* d_in, const int* in_sizes, int n_in,
                              void* d_out, int out_size, void* d_ws, size_t ws_size,
                              hipStream_t stream) {
    const float* t     = (const float*)d_in[0];   // (1,)
    const float* y     = (const float*)d_in[1];   // (32, 1025)
    const float* u     = (const float*)d_in[2];   // (100, 32, 1024)
    const float* A     = (const float*)d_in[3];   // (1024, 1024)
    const float* freqs = (const float*)d_in[4];   // (1024,)
    float* out = (float*)d_out;                   // (32, 1025)

    float* ws_sin = (float*)d_ws;                       // [DIMK][BATCH]
    float* ws_cos = ws_sin + (size_t)DIMK * BATCH;      // [DIMK][BATCH]

    kura_prep<<<BATCH, 256, 0, stream>>>(t, y, u, out, ws_sin, ws_cos);
    kura_main<<<DIMK / RPB, 256, 0, stream>>>(t, u, A, freqs, ws_sin, ws_cos, out);
}

// Round 3
// 80.850 us; speedup vs baseline: 1.0899x; 1.0899x over previous
//
#include <hip/hip_runtime.h>
#include <math.h>

#define DIMK 1024
#define BATCH 32
#define YLD 1025       // y / out leading dim (dim+1)
#define DT_C 0.01f

typedef __attribute__((ext_vector_type(8))) short short8;   // 8 bf16 = 4 VGPRs
typedef __attribute__((ext_vector_type(4))) float f32x4;

static __device__ __forceinline__ unsigned short f2bf(float x) {
    // RNE float -> bf16
    unsigned int u = __float_as_uint(x);
    return (unsigned short)((u + 0x7FFFu + ((u >> 16) & 1u)) >> 16);
}
static __device__ __forceinline__ float bf2f(unsigned short s) {
    return __uint_as_float(((unsigned int)s) << 16);
}

// ---------------- Kernel P: prep + A-convert ----------------
// Blocks 0..31: batch b -> Bt[b][j]=sin(y[b,j]) bf16, Bt[b+32][j]=cos, f1[b].
// Blocks 32..159: convert A (fp32 -> bf16), 8192 floats per block.
__global__ __launch_bounds__(256) void kura_prep(
    const float* __restrict__ t,
    const float* __restrict__ y,
    const float* __restrict__ u,
    const float* __restrict__ A,
    float* __restrict__ out,
    unsigned short* __restrict__ Bt,
    unsigned short* __restrict__ Abf) {
    const int tid = threadIdx.x;
    if (blockIdx.x < BATCH) {
        const int b = blockIdx.x;
        const int idx = (int)floorf(t[0] / DT_C);
        const float* yb = y + (size_t)b * YLD;
        const float* ub = u + (size_t)idx * BATCH * DIMK + (size_t)b * DIMK;
        float acc = 0.f;
        #pragma unroll
        for (int q = 0; q < DIMK / 256; q++) {
            int j = q * 256 + tid;
            float p = yb[j];
            float s = sinf(p);
            float c = cosf(p);
            Bt[(size_t)b * DIMK + j] = f2bf(s);
            Bt[(size_t)(b + BATCH) * DIMK + j] = f2bf(c);
            float f = ub[j];
            acc = fmaf(f, f, acc);
        }
        __shared__ float red[4];
        for (int off = 32; off > 0; off >>= 1)
            acc += __shfl_down(acc, off, 64);
        if ((tid & 63) == 0) red[tid >> 6] = acc;
        __syncthreads();
        if (tid == 0)
            out[(size_t)b * YLD + DIMK] = red[0] + red[1] + red[2] + red[3];
    } else {
        const int blk = blockIdx.x - BATCH;          // 0..127
        const float4* src = (const float4*)A;
        ushort4* dst = (ushort4*)Abf;
        const int base = blk * 2048;                 // float4 units: 1M/4/128
        #pragma unroll
        for (int q = 0; q < 8; q++) {
            int i4 = base + q * 256 + tid;
            float4 a = src[i4];
            ushort4 r;
            r.x = f2bf(a.x); r.y = f2bf(a.y);
            r.z = f2bf(a.z); r.w = f2bf(a.w);
            dst[i4] = r;
        }
    }
}

// ---------------- Kernel G: MFMA GEMM + epilogue ----------------
// D[i][n] = sum_j Abf[i][j] * Bt[n][j]   (M=1024, N=64, K=1024)
// n<32: s-dot for b=n; n>=32: c-dot for b=n-32.
// 64 blocks x 256 thr; wave w owns N-tile [w*16, w*16+16).
__global__ __launch_bounds__(256) void kura_gemm(
    const float* __restrict__ t,
    const float* __restrict__ u,
    const float* __restrict__ freqs,
    const unsigned short* __restrict__ Bt,
    const unsigned short* __restrict__ Abf,
    float* __restrict__ out) {
    __shared__ float Cls[64][20];                    // [n][i_local], padded
    const int tid = threadIdx.x;
    const int l = tid & 63;
    const int w = tid >> 6;
    const int i0 = blockIdx.x * 16;
    const int nl = l & 15;                           // row (A) / col (B) within tile
    const int gr = l >> 4;                           // k-group 0..3

    // Per-lane fragment pointers: lane holds 8 consecutive bf16 along K.
    // Same assumed k-mapping for A and B -> any true k-permutation cancels.
    const short8* Ap = (const short8*)(Abf + (size_t)(i0 + nl) * DIMK + 8 * gr);
    const short8* Bp = (const short8*)(Bt + (size_t)(w * 16 + nl) * DIMK + 8 * gr);

    f32x4 acc = {0.f, 0.f, 0.f, 0.f};
    #pragma unroll 8
    for (int ks = 0; ks < 32; ks++) {                // K=1024 / 32
        short8 av = Ap[ks * 4];                      // +32 bf16 per k-step
        short8 bv = Bp[ks * 4];
        acc = __builtin_amdgcn_mfma_f32_16x16x32_bf16(av, bv, acc, 0, 0, 0);
    }

    // C/D layout: col = lane&15 (=n_local), row = (lane>>4)*4 + reg (=i_local)
    #pragma unroll
    for (int tt = 0; tt < 4; tt++)
        Cls[w * 16 + nl][gr * 4 + tt] = acc[tt];
    __syncthreads();

    const int idx = (int)floorf(t[0] / DT_C);
    const int i = tid & 15;
    #pragma unroll
    for (int h = 0; h < 2; h++) {
        int b = (tid >> 4) + h * 16;
        float aS = Cls[b][i];
        float aC = Cls[b + 32][i];
        float sp = bf2f(Bt[(size_t)b * DIMK + i0 + i]);
        float cp = bf2f(Bt[(size_t)(b + BATCH) * DIMK + i0 + i]);
        float cf = u[(size_t)idx * BATCH * DIMK + (size_t)b * DIMK + i0 + i];
        out[(size_t)b * YLD + i0 + i] =
            fmaf(cf * (cp * aS - sp * aC), 1.0f / (float)DIMK, freqs[i0 + i]);
    }
}

extern "C" void kernel_launch(void* const* d_in, const int* in_sizes, int n_in,
                              void* d_out, int out_size, void* d_ws, size_t ws_size,
                              hipStream_t stream) {
    const float* t     = (const float*)d_in[0];   // (1,)
    const float* y     = (const float*)d_in[1];   // (32, 1025)
    const float* u     = (const float*)d_in[2];   // (100, 32, 1024)
    const float* A     = (const float*)d_in[3];   // (1024, 1024)
    const float* freqs = (const float*)d_in[4];   // (1024,)
    float* out = (float*)d_out;                   // (32, 1025)

    unsigned short* Bt  = (unsigned short*)d_ws;             // [64][1024] bf16
    unsigned short* Abf = Bt + (size_t)2 * BATCH * DIMK;     // [1024][1024] bf16

    kura_prep<<<BATCH + 128, 256, 0, stream>>>(t, y, u, A, out, Bt, Abf);
    kura_gemm<<<DIMK / 16, 256, 0, stream>>>(t, u, freqs, Bt, Abf, out);
}